// Round 10
// baseline (729.826 us; speedup 1.0000x reference)
//
#include <hip/hip_runtime.h>
#include <hip/hip_bf16.h>

// ---------------- model dims ----------------
#define V_  32000
#define D_  768
#define NL_ 2
#define N_  16
#define K_  4
#define DI_ 1536      // E*D
#define DTR 48        // D/16
#define S_  1024

// scan chunking
#define CH_ 16        // chunks
#define TCH 64        // timesteps per chunk
#define DIN (DI_ * N_)   // 24576

// xproj split-K
#define XN  80        // DT_RANK + 2N
#define KS_ 8         // K splits
#define KC_ (DI_ / KS_)  // 192 per chunk

typedef __attribute__((ext_vector_type(8))) short short8;
typedef __attribute__((ext_vector_type(4))) float f32x4;
typedef __attribute__((address_space(3))) void lds_void;
typedef const __attribute__((address_space(1))) void gl_void;

// ---------------- helpers ----------------
__device__ __forceinline__ float silu_f(float x) { return x / (1.f + __expf(-x)); }

__device__ __forceinline__ unsigned short f2bf(float f) {
    unsigned int u = __float_as_uint(f);
    u = (u + 0x7FFFu + ((u >> 16) & 1u)) >> 16;   // RNE
    return (unsigned short)u;
}

// ---------------- fp32 -> bf16 conversion (4 elems/thread) ----------------
__global__ __launch_bounds__(256) void f2bf_k(const float* __restrict__ in,
                                              unsigned short* __restrict__ out, int n) {
    int i = (blockIdx.x * 256 + threadIdx.x) * 4;
    if (i >= n) return;
    float4 v = *(const float4*)(in + i);
    ushort4 o;
    o.x = f2bf(v.x); o.y = f2bf(v.y); o.z = f2bf(v.z); o.w = f2bf(v.w);
    *(ushort4*)(out + i) = o;
}

// ---------------- embedding gather (+ optional bf16 copy) ----------------
__global__ __launch_bounds__(192) void embed_k(const int* __restrict__ tokens,
                                               const float* __restrict__ emb,
                                               float* __restrict__ x,
                                               unsigned short* __restrict__ xbf) {
    int l = blockIdx.x;
    int t = tokens[l];
    const float4* src = (const float4*)(emb + (size_t)t * D_);
    float4 v = src[threadIdx.x];
    *(float4*)(x + (size_t)l * D_ + threadIdx.x * 4) = v;
    if (xbf) {
        ushort4 o;
        o.x = f2bf(v.x); o.y = f2bf(v.y); o.z = f2bf(v.z); o.w = f2bf(v.w);
        *(ushort4*)(xbf + (size_t)l * D_ + threadIdx.x * 4) = o;
    }
}

// ---------------- generic fp32 GEMM:  C[M,N] = A[M,K] * B[N,K]^T ----------------
// Split-K aware: chunk z = blockIdx.z covers A/B columns [z*K, (z+1)*K); the
// partial result is written at C + z*zstride (zstride=0, gridDim.z=1 => plain).
#define BM 128
#define BN 64
#define BK 16
__global__ __launch_bounds__(256) void gemm_nt(const float* __restrict__ A,
                                               const float* __restrict__ B,
                                               float* __restrict__ C,
                                               int M, int N, int K,
                                               int lda, int ldb, int ldc,
                                               int zstride) {
    __shared__ float As[BK][BM + 4];   // pad: 4-way write conflicts -> 2-way (free)
    __shared__ float Bs[BK][BN + 4];

    const int z = blockIdx.z;
    A += (size_t)z * K;
    B += (size_t)z * K;
    C += (size_t)z * zstride;

    const int bm = blockIdx.y * BM;
    const int bn = blockIdx.x * BN;
    const int tid = threadIdx.x;
    const int tx = tid & 15;        // n dir
    const int ty = tid >> 4;        // m dir
    const int arow = tid >> 2;      // 0..63
    const int akq  = (tid & 3) * 4; // k offset

    float acc[8][4];
#pragma unroll
    for (int i = 0; i < 8; ++i)
#pragma unroll
        for (int j = 0; j < 4; ++j) acc[i][j] = 0.f;

    for (int bk = 0; bk < K; bk += BK) {
        float4 a0 = *(const float4*)(A + (size_t)(bm + arow) * lda + bk + akq);
        float4 a1 = *(const float4*)(A + (size_t)(bm + arow + 64) * lda + bk + akq);
        float4 b0 = make_float4(0.f, 0.f, 0.f, 0.f);
        int brow = bn + arow;
        if (brow < N) b0 = *(const float4*)(B + (size_t)brow * ldb + bk + akq);

        __syncthreads();
        As[akq + 0][arow]      = a0.x;
        As[akq + 1][arow]      = a0.y;
        As[akq + 2][arow]      = a0.z;
        As[akq + 3][arow]      = a0.w;
        As[akq + 0][arow + 64] = a1.x;
        As[akq + 1][arow + 64] = a1.y;
        As[akq + 2][arow + 64] = a1.z;
        As[akq + 3][arow + 64] = a1.w;
        Bs[akq + 0][arow] = b0.x;
        Bs[akq + 1][arow] = b0.y;
        Bs[akq + 2][arow] = b0.z;
        Bs[akq + 3][arow] = b0.w;
        __syncthreads();

#pragma unroll
        for (int kk = 0; kk < BK; ++kk) {
            float4 av0 = *(const float4*)&As[kk][ty * 8];
            float4 av1 = *(const float4*)&As[kk][ty * 8 + 4];
            float4 bv  = *(const float4*)&Bs[kk][tx * 4];
            float am[8] = {av0.x, av0.y, av0.z, av0.w, av1.x, av1.y, av1.z, av1.w};
            float bb[4] = {bv.x, bv.y, bv.z, bv.w};
#pragma unroll
            for (int i = 0; i < 8; ++i)
#pragma unroll
                for (int j = 0; j < 4; ++j) acc[i][j] = fmaf(am[i], bb[j], acc[i][j]);
        }
    }

    int ncol = bn + tx * 4;
    if (ncol < N) {
#pragma unroll
        for (int i = 0; i < 8; ++i) {
            int m = bm + ty * 8 + i;
            float4 o = make_float4(acc[i][0], acc[i][1], acc[i][2], acc[i][3]);
            *(float4*)(C + (size_t)m * ldc + ncol) = o;
        }
    }
}

// ---------------- fp32 GEMM + bias + softplus epilogue (dt path) ----------------
__global__ __launch_bounds__(256) void gemm_nt_sp(const float* __restrict__ A,
                                                  const float* __restrict__ B,
                                                  float* __restrict__ C,
                                                  const float* __restrict__ bias,
                                                  int M, int N, int K,
                                                  int lda, int ldb, int ldc) {
    __shared__ float As[BK][BM + 4];
    __shared__ float Bs[BK][BN + 4];

    const int bm = blockIdx.y * BM;
    const int bn = blockIdx.x * BN;
    const int tid = threadIdx.x;
    const int tx = tid & 15;
    const int ty = tid >> 4;
    const int arow = tid >> 2;
    const int akq  = (tid & 3) * 4;

    float acc[8][4];
#pragma unroll
    for (int i = 0; i < 8; ++i)
#pragma unroll
        for (int j = 0; j < 4; ++j) acc[i][j] = 0.f;

    for (int bk = 0; bk < K; bk += BK) {
        float4 a0 = *(const float4*)(A + (size_t)(bm + arow) * lda + bk + akq);
        float4 a1 = *(const float4*)(A + (size_t)(bm + arow + 64) * lda + bk + akq);
        float4 b0 = make_float4(0.f, 0.f, 0.f, 0.f);
        int brow = bn + arow;
        if (brow < N) b0 = *(const float4*)(B + (size_t)brow * ldb + bk + akq);

        __syncthreads();
        As[akq + 0][arow]      = a0.x;
        As[akq + 1][arow]      = a0.y;
        As[akq + 2][arow]      = a0.z;
        As[akq + 3][arow]      = a0.w;
        As[akq + 0][arow + 64] = a1.x;
        As[akq + 1][arow + 64] = a1.y;
        As[akq + 2][arow + 64] = a1.z;
        As[akq + 3][arow + 64] = a1.w;
        Bs[akq + 0][arow] = b0.x;
        Bs[akq + 1][arow] = b0.y;
        Bs[akq + 2][arow] = b0.z;
        Bs[akq + 3][arow] = b0.w;
        __syncthreads();

#pragma unroll
        for (int kk = 0; kk < BK; ++kk) {
            float4 av0 = *(const float4*)&As[kk][ty * 8];
            float4 av1 = *(const float4*)&As[kk][ty * 8 + 4];
            float4 bv  = *(const float4*)&Bs[kk][tx * 4];
            float am[8] = {av0.x, av0.y, av0.z, av0.w, av1.x, av1.y, av1.z, av1.w};
            float bb[4] = {bv.x, bv.y, bv.z, bv.w};
#pragma unroll
            for (int i = 0; i < 8; ++i)
#pragma unroll
                for (int j = 0; j < 4; ++j) acc[i][j] = fmaf(am[i], bb[j], acc[i][j]);
        }
    }

    int ncol = bn + tx * 4;
    if (ncol < N) {
        float bb4[4] = {bias[ncol], bias[ncol + 1], bias[ncol + 2], bias[ncol + 3]};
#pragma unroll
        for (int i = 0; i < 8; ++i) {
            int m = bm + ty * 8 + i;
            float4 o;
            float* op = (float*)&o;
#pragma unroll
            for (int j = 0; j < 4; ++j) {
                float v = acc[i][j] + bb4[j];
                op[j] = (v > 20.f) ? v : log1pf(__expf(v));
            }
            *(float4*)(C + (size_t)m * ldc + ncol) = o;
        }
    }
}

// ---------------- split-K reduce: xdbl[i] = sum_z part[z][i] ----------------
__global__ __launch_bounds__(256) void reduceK_k(const float* __restrict__ part,
                                                 float* __restrict__ out) {
    int i = blockIdx.x * 256 + threadIdx.x;   // over S_*XN
    float s = 0.f;
#pragma unroll
    for (int z = 0; z < KS_; ++z) s += part[(size_t)z * (S_ * XN) + i];
    out[i] = s;
}

// ---------------- bf16 MFMA GEMM: C[M,N] = A[M,K] * B[N,K]^T ----------------
// 128x128 tile, BK=32, 4 waves (2x2), each wave 64x64 (4x4 16x16 frags).
// Grid: dim3(M/128, N/128) — blockIdx.x = M-tile (FASTEST) so the blocks
// sharing one B-panel are dispatch-adjacent => B served from L2/L3, not HBM.
// Requires M%128==0, N%128==0, K%32==0. A,B bf16 bit patterns, C fp32.
__global__ __launch_bounds__(256) void gemm_bf16_nt(const unsigned short* __restrict__ A,
                                                    const unsigned short* __restrict__ B,
                                                    float* __restrict__ C,
                                                    int M, int N, int Kd,
                                                    int lda, int ldb, int ldc) {
    __shared__ unsigned short sA[128 * 32];   // [row][k] linear (global_load_lds order)
    __shared__ unsigned short sB[128 * 32];

    const int tid = threadIdx.x;
    const int w  = tid >> 6;        // wave 0..3
    const int l  = tid & 63;
    const int wm = w >> 1;          // wave row (0..1)
    const int wn = w & 1;           // wave col (0..1)
    const int ln = l & 15;
    const int kq = (l >> 4) << 3;   // 0,8,16,24

    const int bm = blockIdx.x * 128;   // M fastest (B-panel reuse)
    const int bn = blockIdx.y * 128;

    const int srow = tid >> 2;        // 0..63 staging row
    const int skq  = (tid & 3) * 8;   // staging k offset

    f32x4 acc[4][4];
#pragma unroll
    for (int mi = 0; mi < 4; ++mi)
#pragma unroll
        for (int ni = 0; ni < 4; ++ni)
            acc[mi][ni] = (f32x4){0.f, 0.f, 0.f, 0.f};

    for (int bk = 0; bk < Kd; bk += 32) {
        __syncthreads();   // previous compute's LDS reads done
        __builtin_amdgcn_global_load_lds(
            (gl_void*)(A + (size_t)(bm + srow) * lda + bk + skq),
            (lds_void*)(sA + w * 512), 16, 0, 0);
        __builtin_amdgcn_global_load_lds(
            (gl_void*)(A + (size_t)(bm + 64 + srow) * lda + bk + skq),
            (lds_void*)(sA + w * 512 + 2048), 16, 0, 0);
        __builtin_amdgcn_global_load_lds(
            (gl_void*)(B + (size_t)(bn + srow) * ldb + bk + skq),
            (lds_void*)(sB + w * 512), 16, 0, 0);
        __builtin_amdgcn_global_load_lds(
            (gl_void*)(B + (size_t)(bn + 64 + srow) * ldb + bk + skq),
            (lds_void*)(sB + w * 512 + 2048), 16, 0, 0);
        __syncthreads();   // compiler drains vmcnt before barrier

        short8 af[4], bfr[4];
#pragma unroll
        for (int mi = 0; mi < 4; ++mi)
            af[mi] = *(const short8*)(sA + (wm * 64 + mi * 16 + ln) * 32 + kq);
#pragma unroll
        for (int ni = 0; ni < 4; ++ni)
            bfr[ni] = *(const short8*)(sB + (wn * 64 + ni * 16 + ln) * 32 + kq);
#pragma unroll
        for (int mi = 0; mi < 4; ++mi)
#pragma unroll
            for (int ni = 0; ni < 4; ++ni)
                acc[mi][ni] = __builtin_amdgcn_mfma_f32_16x16x32_bf16(
                    af[mi], bfr[ni], acc[mi][ni], 0, 0, 0);
    }

    // epilogue: D row = (lane>>4)*4 + r, col = lane&15  [m89/m91 verified]
    const int r0 = (l >> 4) * 4;
#pragma unroll
    for (int mi = 0; mi < 4; ++mi)
#pragma unroll
        for (int ni = 0; ni < 4; ++ni)
#pragma unroll
            for (int r = 0; r < 4; ++r)
                C[(size_t)(bm + wm * 64 + mi * 16 + r0 + r) * ldc
                  + bn + wn * 64 + ni * 16 + ln] = acc[mi][ni][r];
}

// ---------------- depthwise causal conv1d + bias + silu ----------------
__global__ __launch_bounds__(256) void conv_silu_k(const float* __restrict__ xz,
                                                   const float* __restrict__ cw,
                                                   const float* __restrict__ cb,
                                                   float* __restrict__ xs) {
    int idx = blockIdx.x * 256 + threadIdx.x;      // over S*DI
    int l = idx / DI_;
    int d = idx - l * DI_;
    float acc = cb[d];
    float w0 = cw[d * 4 + 0], w1 = cw[d * 4 + 1], w2 = cw[d * 4 + 2], w3 = cw[d * 4 + 3];
    if (l >= 3) acc = fmaf(xz[(size_t)(l - 3) * (2 * DI_) + d], w0, acc);
    if (l >= 2) acc = fmaf(xz[(size_t)(l - 2) * (2 * DI_) + d], w1, acc);
    if (l >= 1) acc = fmaf(xz[(size_t)(l - 1) * (2 * DI_) + d], w2, acc);
    acc = fmaf(xz[(size_t)l * (2 * DI_) + d], w3, acc);
    xs[idx] = silu_f(acc);
}

// ---------------- chunked selective scan ----------------
__global__ __launch_bounds__(256) void scan_p1(const float* __restrict__ dt,    // [S,DI]
                                               const float* __restrict__ xdbl,  // [S,80]
                                               const float* __restrict__ xs,    // [S,DI]
                                               const float* __restrict__ A_log, // [DI,N]
                                               float* __restrict__ hend,        // [CH,DIN]
                                               float* __restrict__ Pc) {        // [CH,DIN]
    const int c = blockIdx.x / (DIN / 256);
    const int r = (blockIdx.x % (DIN / 256)) * 256 + threadIdx.x;   // 0..DIN-1
    const int d = r >> 4;
    const int n = r & 15;
    const float a = -__expf(A_log[d * N_ + n]);
    float h = 0.f, sdt = 0.f;
    const int l0 = c * TCH;
#pragma unroll 4
    for (int t = 0; t < TCH; ++t) {
        int l = l0 + t;
        float dtv = dt[(size_t)l * DI_ + d];
        float Bv  = xdbl[(size_t)l * XN + 48 + n];
        float xv  = xs[(size_t)l * DI_ + d];
        sdt += dtv;
        h = fmaf(__expf(dtv * a), h, dtv * Bv * xv);
    }
    hend[(size_t)c * DIN + r] = h;
    Pc[(size_t)c * DIN + r]   = __expf(a * sdt);
}

__global__ __launch_bounds__(256) void scan_combine(const float* __restrict__ hend,
                                                    const float* __restrict__ Pc,
                                                    float* __restrict__ hin) {  // [CH,DIN]
    const int r = blockIdx.x * 256 + threadIdx.x;   // 0..DIN-1
    float h = 0.f;
#pragma unroll
    for (int c = 0; c < CH_; ++c) {
        hin[(size_t)c * DIN + r] = h;
        h = fmaf(Pc[(size_t)c * DIN + r], h, hend[(size_t)c * DIN + r]);
    }
}

__global__ __launch_bounds__(256) void scan_p3(const float* __restrict__ dt,
                                               const float* __restrict__ xdbl,
                                               const float* __restrict__ xs,
                                               const float* __restrict__ xz,    // z at [:, DI:]
                                               const float* __restrict__ A_log,
                                               const float* __restrict__ Dp,
                                               const float* __restrict__ hin,
                                               float* __restrict__ y,           // [S,DI]
                                               unsigned short* __restrict__ ybf) {
    const int c = blockIdx.x / (DIN / 256);
    const int r = (blockIdx.x % (DIN / 256)) * 256 + threadIdx.x;
    const int d = r >> 4;
    const int n = r & 15;
    const float a = -__expf(A_log[d * N_ + n]);
    const float Dv = Dp[d];
    float h = hin[(size_t)c * DIN + r];
    const int l0 = c * TCH;
    for (int t = 0; t < TCH; ++t) {
        int l = l0 + t;
        float dtv = dt[(size_t)l * DI_ + d];
        float Bv  = xdbl[(size_t)l * XN + 48 + n];
        float Cv  = xdbl[(size_t)l * XN + 64 + n];
        float xv  = xs[(size_t)l * DI_ + d];
        h = fmaf(__expf(dtv * a), h, dtv * Bv * xv);
        float cv = h * Cv;
        cv += __shfl_xor(cv, 1);
        cv += __shfl_xor(cv, 2);
        cv += __shfl_xor(cv, 4);
        cv += __shfl_xor(cv, 8);
        if (n == 0) {
            float zv = xz[(size_t)l * (2 * DI_) + DI_ + d];
            float out = (cv + xv * Dv) * silu_f(zv);
            y[(size_t)l * DI_ + d] = out;
            if (ybf) ybf[(size_t)l * DI_ + d] = f2bf(out);
        }
    }
}

// ---------------- residual add + layernorm (in place on x, + optional bf16) ----
__global__ __launch_bounds__(256) void res_ln_k(float* __restrict__ x,
                                                const float* __restrict__ mo,
                                                const float* __restrict__ g,
                                                const float* __restrict__ b,
                                                unsigned short* __restrict__ xbf) {
    int l = blockIdx.x;
    int t = threadIdx.x;
    __shared__ float red[4];
    float v[3];
    float s = 0.f;
#pragma unroll
    for (int i = 0; i < 3; ++i) {
        int d = t + i * 256;
        v[i] = x[(size_t)l * D_ + d] + mo[(size_t)l * D_ + d];
        s += v[i];
    }
#pragma unroll
    for (int o = 32; o; o >>= 1) s += __shfl_xor(s, o);
    if ((t & 63) == 0) red[t >> 6] = s;
    __syncthreads();
    float mu = (red[0] + red[1] + red[2] + red[3]) * (1.f / 768.f);
    float vs = 0.f;
#pragma unroll
    for (int i = 0; i < 3; ++i) { float dd = v[i] - mu; vs += dd * dd; }
#pragma unroll
    for (int o = 32; o; o >>= 1) vs += __shfl_xor(vs, o);
    __syncthreads();
    if ((t & 63) == 0) red[t >> 6] = vs;
    __syncthreads();
    float var = (red[0] + red[1] + red[2] + red[3]) * (1.f / 768.f);
    float rstd = rsqrtf(var + 1e-5f);
#pragma unroll
    for (int i = 0; i < 3; ++i) {
        int d = t + i * 256;
        float out = (v[i] - mu) * rstd * g[d] + b[d];
        x[(size_t)l * D_ + d] = out;
        if (xbf) xbf[(size_t)l * D_ + d] = f2bf(out);
    }
}

// ---------------- launcher ----------------
extern "C" void kernel_launch(void* const* d_in, const int* in_sizes, int n_in,
                              void* d_out, int out_size, void* d_ws, size_t ws_size,
                              hipStream_t stream) {
    const int*   tokens  = (const int*)d_in[0];
    const float* emb     = (const float*)d_in[1];
    const float* in_w    = (const float*)d_in[2];
    const float* conv_w  = (const float*)d_in[3];
    const float* conv_b  = (const float*)d_in[4];
    const float* xproj_w = (const float*)d_in[5];
    const float* dt_w    = (const float*)d_in[6];
    const float* dt_b    = (const float*)d_in[7];
    const float* A_log   = (const float*)d_in[8];
    const float* Dp      = (const float*)d_in[9];
    const float* out_w   = (const float*)d_in[10];
    const float* ln_g    = (const float*)d_in[11];
    const float* ln_b    = (const float*)d_in[12];
    const float* head_w  = (const float*)d_in[13];
    float* logits = (float*)d_out;

    float* w = (float*)d_ws;
    float* x    = w;                    // [S, D]
    float* xz   = x    + S_ * D_;       // [S, 2*DI]
    float* xs   = xz   + S_ * 2 * DI_;  // [S, DI]
    float* xdbl = xs   + S_ * DI_;      // [S, 80]
    float* dt   = xdbl + S_ * XN;       // [S, DI]
    float* y    = dt   + S_ * DI_;      // [S, DI]
    float* mo   = y    + S_ * DI_;      // [S, D]
    float* hend = mo   + S_ * D_;       // [CH, DIN]
    float* Pc   = hend + CH_ * DIN;     // [CH, DIN]
    float* hin  = Pc   + CH_ * DIN;     // [CH, DIN]
    // xproj split-K partials reuse hend+Pc (dead until scan_p1): KS_*S_*XN =
    // 655360 floats <= 2*CH_*DIN = 786432 floats.
    float* xpart = hend;
    unsigned short* xbf    = (unsigned short*)(hin + CH_ * DIN);  // [S, D]
    unsigned short* hwbf   = xbf    + (size_t)S_ * D_;            // [V, D]
    unsigned short* ybf    = hwbf   + (size_t)V_ * D_;            // [S, DI]
    unsigned short* inwbf  = ybf    + (size_t)S_ * DI_;           // [NL, 2DI, D]
    unsigned short* outwbf = inwbf  + (size_t)NL_ * 2 * DI_ * D_; // [NL, D, DI]
    unsigned short* wsend  = outwbf + (size_t)NL_ * D_ * DI_;

    const size_t need_head = (size_t)((const char*)ybf   - (const char*)d_ws);
    const size_t need_all  = (size_t)((const char*)wsend - (const char*)d_ws);
    const bool bf_head = ws_size >= need_head;   // deterministic per ws_size
    const bool bf_proj = ws_size >= need_all;

    // weight conversions (independent of layer pipeline)
    if (bf_head)
        f2bf_k<<<(V_ * D_ / 4 + 255) / 256, 256, 0, stream>>>(head_w, hwbf, V_ * D_);
    if (bf_proj) {
        f2bf_k<<<(NL_ * 2 * DI_ * D_ / 4 + 255) / 256, 256, 0, stream>>>(
            in_w, inwbf, NL_ * 2 * DI_ * D_);
        f2bf_k<<<(NL_ * D_ * DI_ / 4 + 255) / 256, 256, 0, stream>>>(
            out_w, outwbf, NL_ * D_ * DI_);
    }

    embed_k<<<S_, 192, 0, stream>>>(tokens, emb, x, bf_head ? xbf : nullptr);

    for (int layer = 0; layer < NL_; ++layer) {
        const float* l_in_w    = in_w    + (size_t)layer * 2 * DI_ * D_;
        const float* l_conv_w  = conv_w  + (size_t)layer * DI_ * K_;
        const float* l_conv_b  = conv_b  + (size_t)layer * DI_;
        const float* l_xproj_w = xproj_w + (size_t)layer * XN * DI_;
        const float* l_dt_w    = dt_w    + (size_t)layer * DI_ * DTR;
        const float* l_dt_b    = dt_b    + (size_t)layer * DI_;
        const float* l_A_log   = A_log   + (size_t)layer * DI_ * N_;
        const float* l_Dp      = Dp      + (size_t)layer * DI_;
        const float* l_out_w   = out_w   + (size_t)layer * D_ * DI_;
        const float* l_ln_g    = ln_g    + (size_t)layer * D_;
        const float* l_ln_b    = ln_b    + (size_t)layer * D_;

        // xz = x @ in_w^T   [1024, 3072]
        if (bf_proj)
            gemm_bf16_nt<<<dim3(S_ / 128, 2 * DI_ / 128), 256, 0, stream>>>(
                xbf, inwbf + (size_t)layer * 2 * DI_ * D_, xz,
                S_, 2 * DI_, D_, D_, D_, 2 * DI_);
        else
            gemm_nt<<<dim3(2 * DI_ / BN, S_ / BM), 256, 0, stream>>>(
                x, l_in_w, xz, S_, 2 * DI_, D_, D_, D_, 2 * DI_, 0);

        conv_silu_k<<<S_ * DI_ / 256, 256, 0, stream>>>(xz, l_conv_w, l_conv_b, xs);

        // x_dbl = xs @ xproj_w^T  [1024, 80] — split-K x8 (latency-bound skinny GEMM)
        gemm_nt<<<dim3((XN + BN - 1) / BN, S_ / BM, KS_), 256, 0, stream>>>(
            xs, l_xproj_w, xpart, S_, XN, KC_, DI_, DI_, XN, S_ * XN);
        reduceK_k<<<S_ * XN / 256, 256, 0, stream>>>(xpart, xdbl);

        // dt = softplus(x_dbl[:, :48] @ dt_w^T + dt_b)  [1024, 1536] — fused epilogue
        gemm_nt_sp<<<dim3(DI_ / BN, S_ / BM), 256, 0, stream>>>(
            xdbl, l_dt_w, dt, l_dt_b, S_, DI_, DTR, XN, DTR, DI_);

        scan_p1<<<CH_ * (DIN / 256), 256, 0, stream>>>(dt, xdbl, xs, l_A_log, hend, Pc);
        scan_combine<<<DIN / 256, 256, 0, stream>>>(hend, Pc, hin);
        scan_p3<<<CH_ * (DIN / 256), 256, 0, stream>>>(
            dt, xdbl, xs, xz, l_A_log, l_Dp, hin, y, bf_proj ? ybf : nullptr);

        // mamba_out = y @ out_w^T  [1024, 768]
        if (bf_proj)
            gemm_bf16_nt<<<dim3(S_ / 128, D_ / 128), 256, 0, stream>>>(
                ybf, outwbf + (size_t)layer * D_ * DI_, mo,
                S_, D_, DI_, DI_, DI_, D_);
        else
            gemm_nt<<<dim3(D_ / BN, S_ / BM), 256, 0, stream>>>(
                y, l_out_w, mo, S_, D_, DI_, DI_, DI_, D_, 0);

        res_ln_k<<<S_, 256, 0, stream>>>(x, mo, l_ln_g, l_ln_b,
                                         bf_head ? xbf : nullptr);
    }

    if (bf_head)
        gemm_bf16_nt<<<dim3(S_ / 128, V_ / 128), 256, 0, stream>>>(
            xbf, hwbf, logits, S_, V_, D_, D_, D_, V_);
    else
        gemm_nt<<<dim3(V_ / BN, S_ / BM), 256, 0, stream>>>(
            x, head_w, logits, S_, V_, D_, D_, D_, V_, 0);
}

// Round 11
// 718.699 us; speedup vs baseline: 1.0155x; 1.0155x over previous
//
#include <hip/hip_runtime.h>
#include <hip/hip_bf16.h>

// ---------------- model dims ----------------
#define V_  32000
#define D_  768
#define NL_ 2
#define N_  16
#define K_  4
#define DI_ 1536      // E*D
#define DTR 48        // D/16
#define S_  1024

// scan chunking
#define CH_ 16        // chunks
#define TCH 64        // timesteps per chunk
#define DIN (DI_ * N_)   // 24576

// xproj split-K
#define XN  80        // DT_RANK + 2N
#define KS_ 8         // K splits
#define KC_ (DI_ / KS_)  // 192 per chunk

typedef __attribute__((ext_vector_type(8))) short short8;
typedef __attribute__((ext_vector_type(4))) float f32x4;
typedef __attribute__((address_space(3))) void lds_void;
typedef const __attribute__((address_space(1))) void gl_void;

// ---------------- helpers ----------------
__device__ __forceinline__ float silu_f(float x) { return x / (1.f + __expf(-x)); }

__device__ __forceinline__ unsigned short f2bf(float f) {
    unsigned int u = __float_as_uint(f);
    u = (u + 0x7FFFu + ((u >> 16) & 1u)) >> 16;   // RNE
    return (unsigned short)u;
}

// ---------------- fp32 -> bf16 conversion (4 elems/thread) ----------------
__global__ __launch_bounds__(256) void f2bf_k(const float* __restrict__ in,
                                              unsigned short* __restrict__ out, int n) {
    int i = (blockIdx.x * 256 + threadIdx.x) * 4;
    if (i >= n) return;
    float4 v = *(const float4*)(in + i);
    ushort4 o;
    o.x = f2bf(v.x); o.y = f2bf(v.y); o.z = f2bf(v.z); o.w = f2bf(v.w);
    *(ushort4*)(out + i) = o;
}

// ---------------- embedding gather (+ optional bf16 copy) ----------------
__global__ __launch_bounds__(192) void embed_k(const int* __restrict__ tokens,
                                               const float* __restrict__ emb,
                                               float* __restrict__ x,
                                               unsigned short* __restrict__ xbf) {
    int l = blockIdx.x;
    int t = tokens[l];
    const float4* src = (const float4*)(emb + (size_t)t * D_);
    float4 v = src[threadIdx.x];
    *(float4*)(x + (size_t)l * D_ + threadIdx.x * 4) = v;
    if (xbf) {
        ushort4 o;
        o.x = f2bf(v.x); o.y = f2bf(v.y); o.z = f2bf(v.z); o.w = f2bf(v.w);
        *(ushort4*)(xbf + (size_t)l * D_ + threadIdx.x * 4) = o;
    }
}

// ---------------- generic fp32 GEMM:  C[M,N] = A[M,K] * B[N,K]^T ----------------
// Split-K aware: chunk z = blockIdx.z covers A/B columns [z*K, (z+1)*K); the
// partial result is written at C + z*zstride (zstride=0, gridDim.z=1 => plain).
#define BM 128
#define BN 64
#define BK 16
__global__ __launch_bounds__(256) void gemm_nt(const float* __restrict__ A,
                                               const float* __restrict__ B,
                                               float* __restrict__ C,
                                               int M, int N, int K,
                                               int lda, int ldb, int ldc,
                                               int zstride) {
    __shared__ float As[BK][BM + 4];   // pad: 4-way write conflicts -> 2-way (free)
    __shared__ float Bs[BK][BN + 4];

    const int z = blockIdx.z;
    A += (size_t)z * K;
    B += (size_t)z * K;
    C += (size_t)z * zstride;

    const int bm = blockIdx.y * BM;
    const int bn = blockIdx.x * BN;
    const int tid = threadIdx.x;
    const int tx = tid & 15;        // n dir
    const int ty = tid >> 4;        // m dir
    const int arow = tid >> 2;      // 0..63
    const int akq  = (tid & 3) * 4; // k offset

    float acc[8][4];
#pragma unroll
    for (int i = 0; i < 8; ++i)
#pragma unroll
        for (int j = 0; j < 4; ++j) acc[i][j] = 0.f;

    for (int bk = 0; bk < K; bk += BK) {
        float4 a0 = *(const float4*)(A + (size_t)(bm + arow) * lda + bk + akq);
        float4 a1 = *(const float4*)(A + (size_t)(bm + arow + 64) * lda + bk + akq);
        float4 b0 = make_float4(0.f, 0.f, 0.f, 0.f);
        int brow = bn + arow;
        if (brow < N) b0 = *(const float4*)(B + (size_t)brow * ldb + bk + akq);

        __syncthreads();
        As[akq + 0][arow]      = a0.x;
        As[akq + 1][arow]      = a0.y;
        As[akq + 2][arow]      = a0.z;
        As[akq + 3][arow]      = a0.w;
        As[akq + 0][arow + 64] = a1.x;
        As[akq + 1][arow + 64] = a1.y;
        As[akq + 2][arow + 64] = a1.z;
        As[akq + 3][arow + 64] = a1.w;
        Bs[akq + 0][arow] = b0.x;
        Bs[akq + 1][arow] = b0.y;
        Bs[akq + 2][arow] = b0.z;
        Bs[akq + 3][arow] = b0.w;
        __syncthreads();

#pragma unroll
        for (int kk = 0; kk < BK; ++kk) {
            float4 av0 = *(const float4*)&As[kk][ty * 8];
            float4 av1 = *(const float4*)&As[kk][ty * 8 + 4];
            float4 bv  = *(const float4*)&Bs[kk][tx * 4];
            float am[8] = {av0.x, av0.y, av0.z, av0.w, av1.x, av1.y, av1.z, av1.w};
            float bb[4] = {bv.x, bv.y, bv.z, bv.w};
#pragma unroll
            for (int i = 0; i < 8; ++i)
#pragma unroll
                for (int j = 0; j < 4; ++j) acc[i][j] = fmaf(am[i], bb[j], acc[i][j]);
        }
    }

    int ncol = bn + tx * 4;
    if (ncol < N) {
#pragma unroll
        for (int i = 0; i < 8; ++i) {
            int m = bm + ty * 8 + i;
            float4 o = make_float4(acc[i][0], acc[i][1], acc[i][2], acc[i][3]);
            *(float4*)(C + (size_t)m * ldc + ncol) = o;
        }
    }
}

// ---------------- fp32 GEMM + bias + softplus epilogue (dt path) ----------------
__global__ __launch_bounds__(256) void gemm_nt_sp(const float* __restrict__ A,
                                                  const float* __restrict__ B,
                                                  float* __restrict__ C,
                                                  const float* __restrict__ bias,
                                                  int M, int N, int K,
                                                  int lda, int ldb, int ldc) {
    __shared__ float As[BK][BM + 4];
    __shared__ float Bs[BK][BN + 4];

    const int bm = blockIdx.y * BM;
    const int bn = blockIdx.x * BN;
    const int tid = threadIdx.x;
    const int tx = tid & 15;
    const int ty = tid >> 4;
    const int arow = tid >> 2;
    const int akq  = (tid & 3) * 4;

    float acc[8][4];
#pragma unroll
    for (int i = 0; i < 8; ++i)
#pragma unroll
        for (int j = 0; j < 4; ++j) acc[i][j] = 0.f;

    for (int bk = 0; bk < K; bk += BK) {
        float4 a0 = *(const float4*)(A + (size_t)(bm + arow) * lda + bk + akq);
        float4 a1 = *(const float4*)(A + (size_t)(bm + arow + 64) * lda + bk + akq);
        float4 b0 = make_float4(0.f, 0.f, 0.f, 0.f);
        int brow = bn + arow;
        if (brow < N) b0 = *(const float4*)(B + (size_t)brow * ldb + bk + akq);

        __syncthreads();
        As[akq + 0][arow]      = a0.x;
        As[akq + 1][arow]      = a0.y;
        As[akq + 2][arow]      = a0.z;
        As[akq + 3][arow]      = a0.w;
        As[akq + 0][arow + 64] = a1.x;
        As[akq + 1][arow + 64] = a1.y;
        As[akq + 2][arow + 64] = a1.z;
        As[akq + 3][arow + 64] = a1.w;
        Bs[akq + 0][arow] = b0.x;
        Bs[akq + 1][arow] = b0.y;
        Bs[akq + 2][arow] = b0.z;
        Bs[akq + 3][arow] = b0.w;
        __syncthreads();

#pragma unroll
        for (int kk = 0; kk < BK; ++kk) {
            float4 av0 = *(const float4*)&As[kk][ty * 8];
            float4 av1 = *(const float4*)&As[kk][ty * 8 + 4];
            float4 bv  = *(const float4*)&Bs[kk][tx * 4];
            float am[8] = {av0.x, av0.y, av0.z, av0.w, av1.x, av1.y, av1.z, av1.w};
            float bb[4] = {bv.x, bv.y, bv.z, bv.w};
#pragma unroll
            for (int i = 0; i < 8; ++i)
#pragma unroll
                for (int j = 0; j < 4; ++j) acc[i][j] = fmaf(am[i], bb[j], acc[i][j]);
        }
    }

    int ncol = bn + tx * 4;
    if (ncol < N) {
        float bb4[4] = {bias[ncol], bias[ncol + 1], bias[ncol + 2], bias[ncol + 3]};
#pragma unroll
        for (int i = 0; i < 8; ++i) {
            int m = bm + ty * 8 + i;
            float4 o;
            float* op = (float*)&o;
#pragma unroll
            for (int j = 0; j < 4; ++j) {
                float v = acc[i][j] + bb4[j];
                op[j] = (v > 20.f) ? v : log1pf(__expf(v));
            }
            *(float4*)(C + (size_t)m * ldc + ncol) = o;
        }
    }
}

// ---------------- split-K reduce: xdbl[i] = sum_z part[z][i] ----------------
__global__ __launch_bounds__(256) void reduceK_k(const float* __restrict__ part,
                                                 float* __restrict__ out) {
    int i = blockIdx.x * 256 + threadIdx.x;   // over S_*XN
    float s = 0.f;
#pragma unroll
    for (int z = 0; z < KS_; ++z) s += part[(size_t)z * (S_ * XN) + i];
    out[i] = s;
}

// ---------------- bf16 MFMA GEMM: C[M,N] = A[M,K] * B[N,K]^T ----------------
// 128x128 tile, BK=32, 4 waves (2x2), each wave 64x64 (4x4 16x16 frags).
// 1D grid, flat = bn_idx * (M/128) + bm_idx (M fastest), then bijective
// XCD swizzle (T1, m204): f = (blk&7)*(nwg/8) + blk>>3, valid since nwg%8==0.
// Each XCD owns a contiguous run of N-panels => B panel reused from its
// private 4MB L2 by all 8 M-tiles instead of 8x HBM/L3 re-fetch.
// Requires M%128==0, N%128==0, K%32==0. A,B bf16 bit patterns, C fp32.
__global__ __launch_bounds__(256) void gemm_bf16_nt(const unsigned short* __restrict__ A,
                                                    const unsigned short* __restrict__ B,
                                                    float* __restrict__ C,
                                                    int M, int N, int Kd,
                                                    int lda, int ldb, int ldc) {
    __shared__ unsigned short sA[128 * 32];   // [row][k] linear (global_load_lds order)
    __shared__ unsigned short sB[128 * 32];

    const int tid = threadIdx.x;
    const int w  = tid >> 6;        // wave 0..3
    const int l  = tid & 63;
    const int wm = w >> 1;          // wave row (0..1)
    const int wn = w & 1;           // wave col (0..1)
    const int ln = l & 15;
    const int kq = (l >> 4) << 3;   // 0,8,16,24

    // XCD-aware bijective swizzle (nwg % 8 == 0 at all call sites)
    const int nwg = gridDim.x;
    const int blk = blockIdx.x;
    const int f   = (blk & 7) * (nwg >> 3) + (blk >> 3);
    const int nbm = M >> 7;
    const int bm = (f % nbm) * 128;
    const int bn = (f / nbm) * 128;

    const int srow = tid >> 2;        // 0..63 staging row
    const int skq  = (tid & 3) * 8;   // staging k offset

    f32x4 acc[4][4];
#pragma unroll
    for (int mi = 0; mi < 4; ++mi)
#pragma unroll
        for (int ni = 0; ni < 4; ++ni)
            acc[mi][ni] = (f32x4){0.f, 0.f, 0.f, 0.f};

    for (int bk = 0; bk < Kd; bk += 32) {
        __syncthreads();   // previous compute's LDS reads done
        __builtin_amdgcn_global_load_lds(
            (gl_void*)(A + (size_t)(bm + srow) * lda + bk + skq),
            (lds_void*)(sA + w * 512), 16, 0, 0);
        __builtin_amdgcn_global_load_lds(
            (gl_void*)(A + (size_t)(bm + 64 + srow) * lda + bk + skq),
            (lds_void*)(sA + w * 512 + 2048), 16, 0, 0);
        __builtin_amdgcn_global_load_lds(
            (gl_void*)(B + (size_t)(bn + srow) * ldb + bk + skq),
            (lds_void*)(sB + w * 512), 16, 0, 0);
        __builtin_amdgcn_global_load_lds(
            (gl_void*)(B + (size_t)(bn + 64 + srow) * ldb + bk + skq),
            (lds_void*)(sB + w * 512 + 2048), 16, 0, 0);
        __syncthreads();   // compiler drains vmcnt before barrier

        short8 af[4], bfr[4];
#pragma unroll
        for (int mi = 0; mi < 4; ++mi)
            af[mi] = *(const short8*)(sA + (wm * 64 + mi * 16 + ln) * 32 + kq);
#pragma unroll
        for (int ni = 0; ni < 4; ++ni)
            bfr[ni] = *(const short8*)(sB + (wn * 64 + ni * 16 + ln) * 32 + kq);
#pragma unroll
        for (int mi = 0; mi < 4; ++mi)
#pragma unroll
            for (int ni = 0; ni < 4; ++ni)
                acc[mi][ni] = __builtin_amdgcn_mfma_f32_16x16x32_bf16(
                    af[mi], bfr[ni], acc[mi][ni], 0, 0, 0);
    }

    // epilogue: D row = (lane>>4)*4 + r, col = lane&15  [m89/m91 verified]
    const int r0 = (l >> 4) * 4;
#pragma unroll
    for (int mi = 0; mi < 4; ++mi)
#pragma unroll
        for (int ni = 0; ni < 4; ++ni)
#pragma unroll
            for (int r = 0; r < 4; ++r)
                C[(size_t)(bm + wm * 64 + mi * 16 + r0 + r) * ldc
                  + bn + wn * 64 + ni * 16 + ln] = acc[mi][ni][r];
}

// ---------------- depthwise causal conv1d + bias + silu ----------------
__global__ __launch_bounds__(256) void conv_silu_k(const float* __restrict__ xz,
                                                   const float* __restrict__ cw,
                                                   const float* __restrict__ cb,
                                                   float* __restrict__ xs) {
    int idx = blockIdx.x * 256 + threadIdx.x;      // over S*DI
    int l = idx / DI_;
    int d = idx - l * DI_;
    float acc = cb[d];
    float w0 = cw[d * 4 + 0], w1 = cw[d * 4 + 1], w2 = cw[d * 4 + 2], w3 = cw[d * 4 + 3];
    if (l >= 3) acc = fmaf(xz[(size_t)(l - 3) * (2 * DI_) + d], w0, acc);
    if (l >= 2) acc = fmaf(xz[(size_t)(l - 2) * (2 * DI_) + d], w1, acc);
    if (l >= 1) acc = fmaf(xz[(size_t)(l - 1) * (2 * DI_) + d], w2, acc);
    acc = fmaf(xz[(size_t)l * (2 * DI_) + d], w3, acc);
    xs[idx] = silu_f(acc);
}

// ---------------- chunked selective scan ----------------
__global__ __launch_bounds__(256) void scan_p1(const float* __restrict__ dt,    // [S,DI]
                                               const float* __restrict__ xdbl,  // [S,80]
                                               const float* __restrict__ xs,    // [S,DI]
                                               const float* __restrict__ A_log, // [DI,N]
                                               float* __restrict__ hend,        // [CH,DIN]
                                               float* __restrict__ Pc) {        // [CH,DIN]
    const int c = blockIdx.x / (DIN / 256);
    const int r = (blockIdx.x % (DIN / 256)) * 256 + threadIdx.x;   // 0..DIN-1
    const int d = r >> 4;
    const int n = r & 15;
    const float a = -__expf(A_log[d * N_ + n]);
    float h = 0.f, sdt = 0.f;
    const int l0 = c * TCH;
#pragma unroll 4
    for (int t = 0; t < TCH; ++t) {
        int l = l0 + t;
        float dtv = dt[(size_t)l * DI_ + d];
        float Bv  = xdbl[(size_t)l * XN + 48 + n];
        float xv  = xs[(size_t)l * DI_ + d];
        sdt += dtv;
        h = fmaf(__expf(dtv * a), h, dtv * Bv * xv);
    }
    hend[(size_t)c * DIN + r] = h;
    Pc[(size_t)c * DIN + r]   = __expf(a * sdt);
}

__global__ __launch_bounds__(256) void scan_combine(const float* __restrict__ hend,
                                                    const float* __restrict__ Pc,
                                                    float* __restrict__ hin) {  // [CH,DIN]
    const int r = blockIdx.x * 256 + threadIdx.x;   // 0..DIN-1
    float h = 0.f;
#pragma unroll
    for (int c = 0; c < CH_; ++c) {
        hin[(size_t)c * DIN + r] = h;
        h = fmaf(Pc[(size_t)c * DIN + r], h, hend[(size_t)c * DIN + r]);
    }
}

__global__ __launch_bounds__(256) void scan_p3(const float* __restrict__ dt,
                                               const float* __restrict__ xdbl,
                                               const float* __restrict__ xs,
                                               const float* __restrict__ xz,    // z at [:, DI:]
                                               const float* __restrict__ A_log,
                                               const float* __restrict__ Dp,
                                               const float* __restrict__ hin,
                                               float* __restrict__ y,           // [S,DI]
                                               unsigned short* __restrict__ ybf) {
    const int c = blockIdx.x / (DIN / 256);
    const int r = (blockIdx.x % (DIN / 256)) * 256 + threadIdx.x;
    const int d = r >> 4;
    const int n = r & 15;
    const float a = -__expf(A_log[d * N_ + n]);
    const float Dv = Dp[d];
    float h = hin[(size_t)c * DIN + r];
    const int l0 = c * TCH;
    for (int t = 0; t < TCH; ++t) {
        int l = l0 + t;
        float dtv = dt[(size_t)l * DI_ + d];
        float Bv  = xdbl[(size_t)l * XN + 48 + n];
        float Cv  = xdbl[(size_t)l * XN + 64 + n];
        float xv  = xs[(size_t)l * DI_ + d];
        h = fmaf(__expf(dtv * a), h, dtv * Bv * xv);
        float cv = h * Cv;
        cv += __shfl_xor(cv, 1);
        cv += __shfl_xor(cv, 2);
        cv += __shfl_xor(cv, 4);
        cv += __shfl_xor(cv, 8);
        if (n == 0) {
            float zv = xz[(size_t)l * (2 * DI_) + DI_ + d];
            float out = (cv + xv * Dv) * silu_f(zv);
            y[(size_t)l * DI_ + d] = out;
            if (ybf) ybf[(size_t)l * DI_ + d] = f2bf(out);
        }
    }
}

// ---------------- residual add + layernorm (in place on x, + optional bf16) ----
__global__ __launch_bounds__(256) void res_ln_k(float* __restrict__ x,
                                                const float* __restrict__ mo,
                                                const float* __restrict__ g,
                                                const float* __restrict__ b,
                                                unsigned short* __restrict__ xbf) {
    int l = blockIdx.x;
    int t = threadIdx.x;
    __shared__ float red[4];
    float v[3];
    float s = 0.f;
#pragma unroll
    for (int i = 0; i < 3; ++i) {
        int d = t + i * 256;
        v[i] = x[(size_t)l * D_ + d] + mo[(size_t)l * D_ + d];
        s += v[i];
    }
#pragma unroll
    for (int o = 32; o; o >>= 1) s += __shfl_xor(s, o);
    if ((t & 63) == 0) red[t >> 6] = s;
    __syncthreads();
    float mu = (red[0] + red[1] + red[2] + red[3]) * (1.f / 768.f);
    float vs = 0.f;
#pragma unroll
    for (int i = 0; i < 3; ++i) { float dd = v[i] - mu; vs += dd * dd; }
#pragma unroll
    for (int o = 32; o; o >>= 1) vs += __shfl_xor(vs, o);
    __syncthreads();
    if ((t & 63) == 0) red[t >> 6] = vs;
    __syncthreads();
    float var = (red[0] + red[1] + red[2] + red[3]) * (1.f / 768.f);
    float rstd = rsqrtf(var + 1e-5f);
#pragma unroll
    for (int i = 0; i < 3; ++i) {
        int d = t + i * 256;
        float out = (v[i] - mu) * rstd * g[d] + b[d];
        x[(size_t)l * D_ + d] = out;
        if (xbf) xbf[(size_t)l * D_ + d] = f2bf(out);
    }
}

// ---------------- launcher ----------------
extern "C" void kernel_launch(void* const* d_in, const int* in_sizes, int n_in,
                              void* d_out, int out_size, void* d_ws, size_t ws_size,
                              hipStream_t stream) {
    const int*   tokens  = (const int*)d_in[0];
    const float* emb     = (const float*)d_in[1];
    const float* in_w    = (const float*)d_in[2];
    const float* conv_w  = (const float*)d_in[3];
    const float* conv_b  = (const float*)d_in[4];
    const float* xproj_w = (const float*)d_in[5];
    const float* dt_w    = (const float*)d_in[6];
    const float* dt_b    = (const float*)d_in[7];
    const float* A_log   = (const float*)d_in[8];
    const float* Dp      = (const float*)d_in[9];
    const float* out_w   = (const float*)d_in[10];
    const float* ln_g    = (const float*)d_in[11];
    const float* ln_b    = (const float*)d_in[12];
    const float* head_w  = (const float*)d_in[13];
    float* logits = (float*)d_out;

    float* w = (float*)d_ws;
    float* x    = w;                    // [S, D]
    float* xz   = x    + S_ * D_;       // [S, 2*DI]
    float* xs   = xz   + S_ * 2 * DI_;  // [S, DI]
    float* xdbl = xs   + S_ * DI_;      // [S, 80]
    float* dt   = xdbl + S_ * XN;       // [S, DI]
    float* y    = dt   + S_ * DI_;      // [S, DI]
    float* mo   = y    + S_ * DI_;      // [S, D]
    float* hend = mo   + S_ * D_;       // [CH, DIN]
    float* Pc   = hend + CH_ * DIN;     // [CH, DIN]
    float* hin  = Pc   + CH_ * DIN;     // [CH, DIN]
    // xproj split-K partials reuse hend+Pc (dead until scan_p1): KS_*S_*XN =
    // 655360 floats <= 2*CH_*DIN = 786432 floats.
    float* xpart = hend;
    unsigned short* xbf    = (unsigned short*)(hin + CH_ * DIN);  // [S, D]
    unsigned short* hwbf   = xbf    + (size_t)S_ * D_;            // [V, D]
    unsigned short* ybf    = hwbf   + (size_t)V_ * D_;            // [S, DI]
    unsigned short* inwbf  = ybf    + (size_t)S_ * DI_;           // [NL, 2DI, D]
    unsigned short* outwbf = inwbf  + (size_t)NL_ * 2 * DI_ * D_; // [NL, D, DI]
    unsigned short* wsend  = outwbf + (size_t)NL_ * D_ * DI_;

    const size_t need_head = (size_t)((const char*)ybf   - (const char*)d_ws);
    const size_t need_all  = (size_t)((const char*)wsend - (const char*)d_ws);
    const bool bf_head = ws_size >= need_head;   // deterministic per ws_size
    const bool bf_proj = ws_size >= need_all;

    // weight conversions (independent of layer pipeline)
    if (bf_head)
        f2bf_k<<<(V_ * D_ / 4 + 255) / 256, 256, 0, stream>>>(head_w, hwbf, V_ * D_);
    if (bf_proj) {
        f2bf_k<<<(NL_ * 2 * DI_ * D_ / 4 + 255) / 256, 256, 0, stream>>>(
            in_w, inwbf, NL_ * 2 * DI_ * D_);
        f2bf_k<<<(NL_ * D_ * DI_ / 4 + 255) / 256, 256, 0, stream>>>(
            out_w, outwbf, NL_ * D_ * DI_);
    }

    embed_k<<<S_, 192, 0, stream>>>(tokens, emb, x, bf_head ? xbf : nullptr);

    for (int layer = 0; layer < NL_; ++layer) {
        const float* l_in_w    = in_w    + (size_t)layer * 2 * DI_ * D_;
        const float* l_conv_w  = conv_w  + (size_t)layer * DI_ * K_;
        const float* l_conv_b  = conv_b  + (size_t)layer * DI_;
        const float* l_xproj_w = xproj_w + (size_t)layer * XN * DI_;
        const float* l_dt_w    = dt_w    + (size_t)layer * DI_ * DTR;
        const float* l_dt_b    = dt_b    + (size_t)layer * DI_;
        const float* l_A_log   = A_log   + (size_t)layer * DI_ * N_;
        const float* l_Dp      = Dp      + (size_t)layer * DI_;
        const float* l_out_w   = out_w   + (size_t)layer * D_ * DI_;
        const float* l_ln_g    = ln_g    + (size_t)layer * D_;
        const float* l_ln_b    = ln_b    + (size_t)layer * D_;

        // xz = x @ in_w^T   [1024, 3072]
        if (bf_proj)
            gemm_bf16_nt<<<(S_ / 128) * (2 * DI_ / 128), 256, 0, stream>>>(
                xbf, inwbf + (size_t)layer * 2 * DI_ * D_, xz,
                S_, 2 * DI_, D_, D_, D_, 2 * DI_);
        else
            gemm_nt<<<dim3(2 * DI_ / BN, S_ / BM), 256, 0, stream>>>(
                x, l_in_w, xz, S_, 2 * DI_, D_, D_, D_, 2 * DI_, 0);

        conv_silu_k<<<S_ * DI_ / 256, 256, 0, stream>>>(xz, l_conv_w, l_conv_b, xs);

        // x_dbl = xs @ xproj_w^T  [1024, 80] — split-K x8 (latency-bound skinny GEMM)
        gemm_nt<<<dim3((XN + BN - 1) / BN, S_ / BM, KS_), 256, 0, stream>>>(
            xs, l_xproj_w, xpart, S_, XN, KC_, DI_, DI_, XN, S_ * XN);
        reduceK_k<<<S_ * XN / 256, 256, 0, stream>>>(xpart, xdbl);

        // dt = softplus(x_dbl[:, :48] @ dt_w^T + dt_b)  [1024, 1536] — fused epilogue
        gemm_nt_sp<<<dim3(DI_ / BN, S_ / BM), 256, 0, stream>>>(
            xdbl, l_dt_w, dt, l_dt_b, S_, DI_, DTR, XN, DTR, DI_);

        scan_p1<<<CH_ * (DIN / 256), 256, 0, stream>>>(dt, xdbl, xs, l_A_log, hend, Pc);
        scan_combine<<<DIN / 256, 256, 0, stream>>>(hend, Pc, hin);
        scan_p3<<<CH_ * (DIN / 256), 256, 0, stream>>>(
            dt, xdbl, xs, xz, l_A_log, l_Dp, hin, y, bf_proj ? ybf : nullptr);

        // mamba_out = y @ out_w^T  [1024, 768]
        if (bf_proj)
            gemm_bf16_nt<<<(S_ / 128) * (D_ / 128), 256, 0, stream>>>(
                ybf, outwbf + (size_t)layer * D_ * DI_, mo,
                S_, D_, DI_, DI_, DI_, D_);
        else
            gemm_nt<<<dim3(D_ / BN, S_ / BM), 256, 0, stream>>>(
                y, l_out_w, mo, S_, D_, DI_, DI_, DI_, D_, 0);

        res_ln_k<<<S_, 256, 0, stream>>>(x, mo, l_ln_g, l_ln_b,
                                         bf_head ? xbf : nullptr);
    }

    if (bf_head)
        gemm_bf16_nt<<<(S_ / 128) * (V_ / 128), 256, 0, stream>>>(
            xbf, hwbf, logits, S_, V_, D_, D_, D_, V_);
    else
        gemm_nt<<<dim3(V_ / BN, S_ / BM), 256, 0, stream>>>(
            x, head_w, logits, S_, V_, D_, D_, D_, V_, 0);
}